// Round 4
// baseline (298.556 us; speedup 1.0000x reference)
//
#include <hip/hip_runtime.h>
#include <hip/hip_fp16.h>

#define CLIP_HI (1.0f - 1e-6f)

typedef float f4v __attribute__((ext_vector_type(4)));

__device__ __forceinline__ float tri_(float x) {
    return 2.0f * fabsf(x * 0.5f - floorf(x * 0.5f + 0.5f));
}

__device__ __forceinline__ float clamp01(float x) {
    return fminf(fmaxf(x, 0.0f), CLIP_HI);
}

__device__ __forceinline__ float4 nt_load4(const float* p) {
    f4v v = __builtin_nontemporal_load((const f4v*)p);
    return make_float4(v.x, v.y, v.z, v.w);
}
__device__ __forceinline__ void nt_store4(float* p, float4 v) {
    f4v t = {v.x, v.y, v.z, v.w};
    __builtin_nontemporal_store(t, (f4v*)p);
}

// 8-byte half4 payload: one ds_read_b64 / global_load_dwordx2 per sample.
struct H4 { __half2 xy, zw; };

struct BW {
    int i00, i10, i01, i11;
    float w00, w10, w01, w11;
};

template <int U, int V>
__device__ __forceinline__ BW bw2d(float uc, float vc) {
    float u = clamp01(uc) * (float)(U - 1);
    float v = clamp01(vc) * (float)(V - 1);
    float u0f = floorf(u), v0f = floorf(v);
    float fu = u - u0f, fv = v - v0f;
    int u0 = (int)u0f, v0 = (int)v0f;
    int u1 = min(u0 + 1, U - 1);
    int v1 = min(v0 + 1, V - 1);
    BW r;
    r.i00 = u0 * V + v0;
    r.i10 = u1 * V + v0;
    r.i01 = u0 * V + v1;
    r.i11 = u1 * V + v1;
    float gu = 1.0f - fu, gv = 1.0f - fv;
    r.w00 = gu * gv; r.w10 = fu * gv; r.w01 = gu * fv; r.w11 = fu * fv;
    return r;
}

__device__ __forceinline__ float4 h4_blend(H4 A, H4 B, H4 C, H4 D, const BW& b) {
    float2 Axy = __half22float2(A.xy), Azw = __half22float2(A.zw);
    float2 Bxy = __half22float2(B.xy), Bzw = __half22float2(B.zw);
    float2 Cxy = __half22float2(C.xy), Czw = __half22float2(C.zw);
    float2 Dxy = __half22float2(D.xy), Dzw = __half22float2(D.zw);
    return make_float4(
        Axy.x * b.w00 + Bxy.x * b.w10 + Cxy.x * b.w01 + Dxy.x * b.w11,
        Axy.y * b.w00 + Bxy.y * b.w10 + Cxy.y * b.w01 + Dxy.y * b.w11,
        Azw.x * b.w00 + Bzw.x * b.w10 + Czw.x * b.w01 + Dzw.x * b.w11,
        Azw.y * b.w00 + Bzw.y * b.w10 + Czw.y * b.w01 + Dzw.y * b.w11);
}

// Prep: tabRSEnc (64,64,3) -> (64,64) half4 in d_ws, tri() applied. 32 KB -> L1-resident.
__global__ __launch_bounds__(256) void prep_rs_kernel(const float* __restrict__ t,
                                                      H4* __restrict__ o) {
    int j = blockIdx.x * 256 + threadIdx.x;
    if (j < 64 * 64) {
        float a = tri_(t[j * 3 + 0]);
        float b = tri_(t[j * 3 + 1]);
        float c = tri_(t[j * 3 + 2]);
        H4 h;
        h.xy = __floats2half2_rn(a, b);
        h.zw = __floats2half2_rn(c, 0.0f);
        o[j] = h;
    }
}

// RAEnc nearest-neighbor gather address + load (issue early; consume later).
__device__ __forceinline__ float2 gatherRA(const float* __restrict__ tabRAEnc,
                                           float rNx, float aTx) {
    int ui = (int)rintf(clamp01(rNx) * 2047.0f);   // jnp.round = half-to-even
    int vi = (int)rintf(clamp01(aTx) * 2047.0f);
    return ((const float2*)tabRAEnc)[ui * 2048 + vi];
}

// Everything after the RAEnc gather. raT passed in (already in flight).
template <bool USE_WS>
__device__ __forceinline__ float2 shadeB(
    float rNx, float rNy, float aTy, float nLVx, float nLVy,
    float mLx, float mLy, float sCx, float sCy, float spx, float spy,
    float shx, float shy, float lCx, float lCy,
    float2 raT,
    const float* __restrict__ tabRSEnc, const H4* __restrict__ rsPacked,
    const float* sRADec, const float2* sCgComp, const float* sLVR,
    const H4* sLV, const H4* sNHL)
{
    // --- rsEnc bilinear (global, 32 KB L1-resident when USE_WS) ---
    float rs0, rs1, rs2;
    {
        BW b = bw2d<64, 64>(rNx, sCx);
        if constexpr (USE_WS) {
            float4 r = h4_blend(rsPacked[b.i00], rsPacked[b.i10],
                                rsPacked[b.i01], rsPacked[b.i11], b);
            rs0 = r.x; rs1 = r.y; rs2 = r.z;
        } else {
            const float* p00 = tabRSEnc + b.i00 * 3;
            const float* p10 = tabRSEnc + b.i10 * 3;
            const float* p01 = tabRSEnc + b.i01 * 3;
            const float* p11 = tabRSEnc + b.i11 * 3;
            rs0 = tri_(p00[0]) * b.w00 + tri_(p10[0]) * b.w10 + tri_(p01[0]) * b.w01 + tri_(p11[0]) * b.w11;
            rs1 = tri_(p00[1]) * b.w00 + tri_(p10[1]) * b.w10 + tri_(p01[1]) * b.w01 + tri_(p11[1]) * b.w11;
            rs2 = tri_(p00[2]) * b.w00 + tri_(p10[2]) * b.w10 + tri_(p01[2]) * b.w01 + tri_(p11[2]) * b.w11;
        }
    }

    // --- composed cg lookup: one LDS float2 read ---
    float2 cgC = sCgComp[(int)rintf(clamp01(sCy) * 2047.0f)];

    // --- nlv, nhl (LDS half4) ---
    float4 nlv, nhl;
    {
        BW b = bw2d<32, 32>(nLVx, nLVy);
        nlv = h4_blend(sLV[b.i00], sLV[b.i10], sLV[b.i01], sLV[b.i11], b);
    }
    {
        BW b = bw2d<32, 32>(mLy, nLVx);
        nhl = h4_blend(sNHL[b.i00], sNHL[b.i10], sNHL[b.i01], sNHL[b.i11], b);
    }

    // --- dependent on RAEnc gather result ---
    float ra0 = tri_(raT.x);
    float ra1 = tri_(raT.y);

    float raC0, raC1, raC2;
    {
        BW b = bw2d<48, 48>(ra0, ra1);
        const float* p00 = &sRADec[b.i00 * 3];
        const float* p10 = &sRADec[b.i10 * 3];
        const float* p01 = &sRADec[b.i01 * 3];
        const float* p11 = &sRADec[b.i11 * 3];
        raC0 = p00[0] * b.w00 + p10[0] * b.w10 + p01[0] * b.w01 + p11[0] * b.w11;
        raC1 = p00[1] * b.w00 + p10[1] * b.w10 + p01[1] * b.w01 + p11[1] * b.w11;
        raC2 = p00[2] * b.w00 + p10[2] * b.w10 + p01[2] * b.w01 + p11[2] * b.w11;
    }

    float vTerm;
    {
        BW b = bw2d<32, 32>(nLVx * nLVy, ra0);
        vTerm = sLVR[b.i00] * b.w00 + sLVR[b.i10] * b.w10 +
                sLVR[b.i01] * b.w01 + sLVR[b.i11] * b.w11;
    }

    // --- epilogue arithmetic ---
    float met = mLx;
    float om  = 1.0f - met;
    float cd  = om * lCx;
    float cm0 = spx * 0.1f * om * spy + met * lCx;
    float cm1 = spx * 0.1f * om * (1.0f - spy);
    float cs0 = shx * om * shy;
    float cs1 = shx * om * (1.0f - shy);
    float cc  = 0.0625f * lCy;

    float noh2 = rNy * rNy;
    float den  = raC0 * aTy * aTy + raC1 * noh2 + raC2;
    float dTerm = 0.25f / (nLVy * den * den);

    float x = rs0 * cd * mLy * nlv.y + rs1 * cd * nlv.z + rs2 * cd * nlv.w
            + cm0 * vTerm * nhl.z * dTerm + cs0 * nhl.x;

    float y = ((1.0f - cm1) * nhl.w + cm1) * vTerm * dTerm
            + cs1 * nhl.x
            + cc * nhl.y * nlv.x / (nLVy * (cgC.x * noh2 + cgC.y));

    return make_float2(x, y);
}

template <bool USE_WS>
__global__ __launch_bounds__(1024, 8) void disney_main(
    const float* __restrict__ roughNoh,
    const float* __restrict__ anisoToh,
    const float* __restrict__ nDotLV,
    const float* __restrict__ metalLoh,
    const float* __restrict__ subCg,
    const float* __restrict__ spst,
    const float* __restrict__ shst,
    const float* __restrict__ lumCs,
    const float* __restrict__ tabRAEnc,   // (2048,2048,2) global gather
    const float* __restrict__ tabCgEnc,   // (2048,1)  composed -> LDS
    const float* __restrict__ tabRSEnc,   // (64,64,3) fallback path
    const H4*    __restrict__ rsPacked,   // (64,64) half4 in d_ws, tri'd
    const float* __restrict__ tabRADec,   // (48,48,3) -> LDS fp32
    const float* __restrict__ tabCgDec,   // (96,2)    composed -> LDS
    const float* __restrict__ tabLVR,     // (32,32,1) -> LDS fp32 (tri'd)
    const float* __restrict__ tabLV,      // (32,32,4) -> LDS half4 (tri'd)
    const float* __restrict__ tabNHL,     // (32,32,4) -> LDS half4 (tri'd)
    float* __restrict__ out,
    int n)
{
    // 64512 B total (<=64 KB static): 2 blocks/CU -> 32 waves/CU.
    __shared__ float  sRADec[48 * 48 * 3];   // 27648 B (denominator-critical, fp32)
    __shared__ float2 sCgComp[2048];         // 16384 B composed cgEnc∘cgDec
    __shared__ float  sLVR[1024];            //  4096 B
    __shared__ H4     sLV[1024];             //  8192 B
    __shared__ H4     sNHL[1024];            //  8192 B

    int tid = threadIdx.x;

    for (int j = tid; j < 48 * 48 * 3; j += 1024) sRADec[j] = tabRADec[j];
#pragma unroll
    for (int k = 0; k < 2; ++k) {
        int j = tid + k * 1024;
        // compose: cg = tri(cgEnc[j]); cgCoefs = lerp(cgDec, clamp01(cg)*95)
        float cg = tri_(tabCgEnc[j]);
        float u = clamp01(cg) * 95.0f;
        float u0f = floorf(u);
        float fu = u - u0f;
        int u0 = (int)u0f;
        int u1 = min(u0 + 1, 95);
        float2 a = ((const float2*)tabCgDec)[u0];
        float2 b = ((const float2*)tabCgDec)[u1];
        sCgComp[j] = make_float2(a.x * (1.0f - fu) + b.x * fu,
                                 a.y * (1.0f - fu) + b.y * fu);
    }
    sLVR[tid] = tri_(tabLVR[tid]);
    {
        float4 v = ((const float4*)tabLV)[tid];
        H4 h; h.xy = __floats2half2_rn(tri_(v.x), tri_(v.y));
              h.zw = __floats2half2_rn(tri_(v.z), tri_(v.w));
        sLV[tid] = h;
    }
    {
        float4 v = ((const float4*)tabNHL)[tid];
        H4 h; h.xy = __floats2half2_rn(tri_(v.x), tri_(v.y));
              h.zw = __floats2half2_rn(tri_(v.z), tri_(v.w));
        sNHL[tid] = h;
    }
    __syncthreads();

    // this thread owns elements [4g, 4g+4)
    int g = blockIdx.x * 1024 + tid;
    int e0 = 4 * g;
    if (e0 >= n) return;

    if (e0 + 3 < n) {
        // ---- full group: issue all 4 long-latency RAEnc gathers first ----
        float4 rNa = nt_load4(roughNoh + 8 * g);
        float4 rNb = nt_load4(roughNoh + 8 * g + 4);
        float4 aTa = nt_load4(anisoToh + 8 * g);
        float4 aTb = nt_load4(anisoToh + 8 * g + 4);

        float2 raT0 = gatherRA(tabRAEnc, rNa.x, aTa.x);
        float2 raT1 = gatherRA(tabRAEnc, rNa.z, aTa.z);
        float2 raT2 = gatherRA(tabRAEnc, rNb.x, aTb.x);
        float2 raT3 = gatherRA(tabRAEnc, rNb.z, aTb.z);

        // ---- pair A (elements 0,1) ----
        {
            float4 nLV = nt_load4(nDotLV   + 8 * g);
            float4 mL  = nt_load4(metalLoh + 8 * g);
            float4 sC  = nt_load4(subCg    + 8 * g);
            float4 sp  = nt_load4(spst     + 8 * g);
            float4 sh  = nt_load4(shst     + 8 * g);
            float4 lC  = nt_load4(lumCs    + 8 * g);
            float2 r0 = shadeB<USE_WS>(rNa.x, rNa.y, aTa.y, nLV.x, nLV.y,
                                       mL.x, mL.y, sC.x, sC.y, sp.x, sp.y,
                                       sh.x, sh.y, lC.x, lC.y, raT0,
                                       tabRSEnc, rsPacked,
                                       sRADec, sCgComp, sLVR, sLV, sNHL);
            float2 r1 = shadeB<USE_WS>(rNa.z, rNa.w, aTa.w, nLV.z, nLV.w,
                                       mL.z, mL.w, sC.z, sC.w, sp.z, sp.w,
                                       sh.z, sh.w, lC.z, lC.w, raT1,
                                       tabRSEnc, rsPacked,
                                       sRADec, sCgComp, sLVR, sLV, sNHL);
            nt_store4(out + 8 * g, make_float4(r0.x, r0.y, r1.x, r1.y));
        }
        // ---- pair B (elements 2,3) ----
        {
            float4 nLV = nt_load4(nDotLV   + 8 * g + 4);
            float4 mL  = nt_load4(metalLoh + 8 * g + 4);
            float4 sC  = nt_load4(subCg    + 8 * g + 4);
            float4 sp  = nt_load4(spst     + 8 * g + 4);
            float4 sh  = nt_load4(shst     + 8 * g + 4);
            float4 lC  = nt_load4(lumCs    + 8 * g + 4);
            float2 r2 = shadeB<USE_WS>(rNb.x, rNb.y, aTb.y, nLV.x, nLV.y,
                                       mL.x, mL.y, sC.x, sC.y, sp.x, sp.y,
                                       sh.x, sh.y, lC.x, lC.y, raT2,
                                       tabRSEnc, rsPacked,
                                       sRADec, sCgComp, sLVR, sLV, sNHL);
            float2 r3 = shadeB<USE_WS>(rNb.z, rNb.w, aTb.w, nLV.z, nLV.w,
                                       mL.z, mL.w, sC.z, sC.w, sp.z, sp.w,
                                       sh.z, sh.w, lC.z, lC.w, raT3,
                                       tabRSEnc, rsPacked,
                                       sRADec, sCgComp, sLVR, sLV, sNHL);
            nt_store4(out + 8 * g + 4, make_float4(r2.x, r2.y, r3.x, r3.y));
        }
    } else {
        // ---- tail: per-element scalar path ----
        for (int e = e0; e < n; ++e) {
            float2 rN  = ((const float2*)roughNoh)[e];
            float2 aT  = ((const float2*)anisoToh)[e];
            float2 nLV = ((const float2*)nDotLV)[e];
            float2 mL  = ((const float2*)metalLoh)[e];
            float2 sC  = ((const float2*)subCg)[e];
            float2 sp  = ((const float2*)spst)[e];
            float2 sh  = ((const float2*)shst)[e];
            float2 lC  = ((const float2*)lumCs)[e];
            float2 raT = gatherRA(tabRAEnc, rN.x, aT.x);
            float2 r = shadeB<USE_WS>(rN.x, rN.y, aT.y, nLV.x, nLV.y,
                                      mL.x, mL.y, sC.x, sC.y, sp.x, sp.y,
                                      sh.x, sh.y, lC.x, lC.y, raT,
                                      tabRSEnc, rsPacked,
                                      sRADec, sCgComp, sLVR, sLV, sNHL);
            ((float2*)out)[e] = r;
        }
    }
}

extern "C" void kernel_launch(void* const* d_in, const int* in_sizes, int n_in,
                              void* d_out, int out_size, void* d_ws, size_t ws_size,
                              hipStream_t stream) {
    // 0 roughNoh, 1 anisoToh, 2 nDotLV, 3 tDotLV (UNUSED), 4 metalLoh,
    // 5 subCg, 6 spst, 7 shst, 8 lumCs, 9 tabRAEnc, 10 tabCgEnc, 11 tabRSEnc,
    // 12 tabRADec, 13 tabCgDec, 14 tabLVR, 15 tabLV, 16 tabNHL
    const float* roughNoh = (const float*)d_in[0];
    const float* anisoToh = (const float*)d_in[1];
    const float* nDotLV   = (const float*)d_in[2];
    const float* metalLoh = (const float*)d_in[4];
    const float* subCg    = (const float*)d_in[5];
    const float* spst     = (const float*)d_in[6];
    const float* shst     = (const float*)d_in[7];
    const float* lumCs    = (const float*)d_in[8];
    const float* tabRAEnc = (const float*)d_in[9];
    const float* tabCgEnc = (const float*)d_in[10];
    const float* tabRSEnc = (const float*)d_in[11];
    const float* tabRADec = (const float*)d_in[12];
    const float* tabCgDec = (const float*)d_in[13];
    const float* tabLVR   = (const float*)d_in[14];
    const float* tabLV    = (const float*)d_in[15];
    const float* tabNHL   = (const float*)d_in[16];

    int n = in_sizes[0] / 2;   // (N,2)
    float* out = (float*)d_out;

    const int block = 1024;
    int groups = (n + 3) / 4;
    int grid = (groups + block - 1) / block;

    bool use_ws = ws_size >= (size_t)(64 * 64 * sizeof(H4));
    if (use_ws) {
        prep_rs_kernel<<<(64 * 64 + 255) / 256, 256, 0, stream>>>(tabRSEnc, (H4*)d_ws);
        disney_main<true><<<grid, block, 0, stream>>>(
            roughNoh, anisoToh, nDotLV, metalLoh, subCg, spst, shst, lumCs,
            tabRAEnc, tabCgEnc, tabRSEnc, (const H4*)d_ws,
            tabRADec, tabCgDec, tabLVR, tabLV, tabNHL, out, n);
    } else {
        disney_main<false><<<grid, block, 0, stream>>>(
            roughNoh, anisoToh, nDotLV, metalLoh, subCg, spst, shst, lumCs,
            tabRAEnc, tabCgEnc, tabRSEnc, (const H4*)d_ws,
            tabRADec, tabCgDec, tabLVR, tabLV, tabNHL, out, n);
    }
}

// Round 5
// 235.811 us; speedup vs baseline: 1.2661x; 1.2661x over previous
//
#include <hip/hip_runtime.h>
#include <hip/hip_fp16.h>

#define CLIP_HI (1.0f - 1e-6f)

typedef float f4v __attribute__((ext_vector_type(4)));

__device__ __forceinline__ float tri_(float x) {
    return 2.0f * fabsf(x * 0.5f - floorf(x * 0.5f + 0.5f));
}

__device__ __forceinline__ float clamp01(float x) {
    return fminf(fmaxf(x, 0.0f), CLIP_HI);
}

__device__ __forceinline__ float4 nt_load4(const float* p) {
    f4v v = __builtin_nontemporal_load((const f4v*)p);
    return make_float4(v.x, v.y, v.z, v.w);
}
__device__ __forceinline__ void nt_store4(float* p, float4 v) {
    f4v t = {v.x, v.y, v.z, v.w};
    __builtin_nontemporal_store(t, (f4v*)p);
}

// 8-byte half4 payload: one ds_read_b64 / global_load_dwordx2 per sample.
struct H4 { __half2 xy, zw; };

struct BW {
    int i00, i10, i01, i11;
    float w00, w10, w01, w11;
};

template <int U, int V>
__device__ __forceinline__ BW bw2d(float uc, float vc) {
    float u = clamp01(uc) * (float)(U - 1);
    float v = clamp01(vc) * (float)(V - 1);
    float u0f = floorf(u), v0f = floorf(v);
    float fu = u - u0f, fv = v - v0f;
    int u0 = (int)u0f, v0 = (int)v0f;
    int u1 = min(u0 + 1, U - 1);
    int v1 = min(v0 + 1, V - 1);
    BW r;
    r.i00 = u0 * V + v0;
    r.i10 = u1 * V + v0;
    r.i01 = u0 * V + v1;
    r.i11 = u1 * V + v1;
    float gu = 1.0f - fu, gv = 1.0f - fv;
    r.w00 = gu * gv; r.w10 = fu * gv; r.w01 = gu * fv; r.w11 = fu * fv;
    return r;
}

__device__ __forceinline__ float4 h4_blend(H4 A, H4 B, H4 C, H4 D, const BW& b) {
    float2 Axy = __half22float2(A.xy), Azw = __half22float2(A.zw);
    float2 Bxy = __half22float2(B.xy), Bzw = __half22float2(B.zw);
    float2 Cxy = __half22float2(C.xy), Czw = __half22float2(C.zw);
    float2 Dxy = __half22float2(D.xy), Dzw = __half22float2(D.zw);
    return make_float4(
        Axy.x * b.w00 + Bxy.x * b.w10 + Cxy.x * b.w01 + Dxy.x * b.w11,
        Axy.y * b.w00 + Bxy.y * b.w10 + Cxy.y * b.w01 + Dxy.y * b.w11,
        Azw.x * b.w00 + Bzw.x * b.w10 + Czw.x * b.w01 + Dzw.x * b.w11,
        Azw.y * b.w00 + Bzw.y * b.w10 + Czw.y * b.w01 + Dzw.y * b.w11);
}

// Prep: tabRSEnc (64,64,3) -> (64,64) half4 in d_ws, tri() applied. 32 KB -> L1-resident.
__global__ __launch_bounds__(256) void prep_rs_kernel(const float* __restrict__ t,
                                                      H4* __restrict__ o) {
    int j = blockIdx.x * 256 + threadIdx.x;
    if (j < 64 * 64) {
        float a = tri_(t[j * 3 + 0]);
        float b = tri_(t[j * 3 + 1]);
        float c = tri_(t[j * 3 + 2]);
        H4 h;
        h.xy = __floats2half2_rn(a, b);
        h.zw = __floats2half2_rn(c, 0.0f);
        o[j] = h;
    }
}

// RAEnc nearest-neighbor gather (issue early; consume later).
__device__ __forceinline__ float2 gatherRA(const float* __restrict__ tabRAEnc,
                                           float rNx, float aTx) {
    int ui = (int)rintf(clamp01(rNx) * 2047.0f);   // jnp.round = half-to-even
    int vi = (int)rintf(clamp01(aTx) * 2047.0f);
    return ((const float2*)tabRAEnc)[ui * 2048 + vi];
}

// Everything after the RAEnc gather. raT passed in (already in flight).
template <bool USE_WS>
__device__ __forceinline__ float2 shadeB(
    float rNx, float rNy, float aTy, float nLVx, float nLVy,
    float mLx, float mLy, float sCx, float sCy, float spx, float spy,
    float shx, float shy, float lCx, float lCy,
    float2 raT,
    const float* __restrict__ tabRSEnc, const H4* __restrict__ rsPacked,
    const H4* sRADec, const __half2* sCgComp, const __half* sLVR,
    const H4* sLV, const H4* sNHL)
{
    // --- rsEnc bilinear (global, 32 KB L1-resident when USE_WS) ---
    float rs0, rs1, rs2;
    {
        BW b = bw2d<64, 64>(rNx, sCx);
        if constexpr (USE_WS) {
            float4 r = h4_blend(rsPacked[b.i00], rsPacked[b.i10],
                                rsPacked[b.i01], rsPacked[b.i11], b);
            rs0 = r.x; rs1 = r.y; rs2 = r.z;
        } else {
            const float* p00 = tabRSEnc + b.i00 * 3;
            const float* p10 = tabRSEnc + b.i10 * 3;
            const float* p01 = tabRSEnc + b.i01 * 3;
            const float* p11 = tabRSEnc + b.i11 * 3;
            rs0 = tri_(p00[0]) * b.w00 + tri_(p10[0]) * b.w10 + tri_(p01[0]) * b.w01 + tri_(p11[0]) * b.w11;
            rs1 = tri_(p00[1]) * b.w00 + tri_(p10[1]) * b.w10 + tri_(p01[1]) * b.w01 + tri_(p11[1]) * b.w11;
            rs2 = tri_(p00[2]) * b.w00 + tri_(p10[2]) * b.w10 + tri_(p01[2]) * b.w01 + tri_(p11[2]) * b.w11;
        }
    }

    // --- composed cgEnc∘cgDec lookup: one LDS half2 read ---
    float2 cgC = __half22float2(sCgComp[(int)rintf(clamp01(sCy) * 2047.0f)]);

    // --- nlv, nhl (LDS half4) ---
    float4 nlv, nhl;
    {
        BW b = bw2d<32, 32>(nLVx, nLVy);
        nlv = h4_blend(sLV[b.i00], sLV[b.i10], sLV[b.i01], sLV[b.i11], b);
    }
    {
        BW b = bw2d<32, 32>(mLy, nLVx);
        nhl = h4_blend(sNHL[b.i00], sNHL[b.i10], sNHL[b.i01], sNHL[b.i11], b);
    }

    // --- dependent on RAEnc gather result ---
    float ra0 = tri_(raT.x);
    float ra1 = tri_(raT.y);

    float raC0, raC1, raC2;
    {
        BW b = bw2d<48, 48>(ra0, ra1);
        float4 r = h4_blend(sRADec[b.i00], sRADec[b.i10],
                            sRADec[b.i01], sRADec[b.i11], b);
        raC0 = r.x; raC1 = r.y; raC2 = r.z;
    }

    float vTerm;
    {
        BW b = bw2d<32, 32>(nLVx * nLVy, ra0);
        vTerm = __half2float(sLVR[b.i00]) * b.w00 + __half2float(sLVR[b.i10]) * b.w10 +
                __half2float(sLVR[b.i01]) * b.w01 + __half2float(sLVR[b.i11]) * b.w11;
    }

    // --- epilogue arithmetic ---
    float met = mLx;
    float om  = 1.0f - met;
    float cd  = om * lCx;
    float cm0 = spx * 0.1f * om * spy + met * lCx;
    float cm1 = spx * 0.1f * om * (1.0f - spy);
    float cs0 = shx * om * shy;
    float cs1 = shx * om * (1.0f - shy);
    float cc  = 0.0625f * lCy;

    float noh2 = rNy * rNy;
    float den  = raC0 * aTy * aTy + raC1 * noh2 + raC2;
    float dTerm = 0.25f / (nLVy * den * den);

    float x = rs0 * cd * mLy * nlv.y + rs1 * cd * nlv.z + rs2 * cd * nlv.w
            + cm0 * vTerm * nhl.z * dTerm + cs0 * nhl.x;

    float y = ((1.0f - cm1) * nhl.w + cm1) * vTerm * dTerm
            + cs1 * nhl.x
            + cc * nhl.y * nlv.x / (nLVy * (cgC.x * noh2 + cgC.y));

    return make_float2(x, y);
}

template <bool USE_WS>
__global__ __launch_bounds__(512, 6) void disney_main(
    const float* __restrict__ roughNoh,
    const float* __restrict__ anisoToh,
    const float* __restrict__ nDotLV,
    const float* __restrict__ metalLoh,
    const float* __restrict__ subCg,
    const float* __restrict__ spst,
    const float* __restrict__ shst,
    const float* __restrict__ lumCs,
    const float* __restrict__ tabRAEnc,   // (2048,2048,2) global gather
    const float* __restrict__ tabCgEnc,   // (2048,1)  composed -> LDS half2
    const float* __restrict__ tabRSEnc,   // (64,64,3) fallback path
    const H4*    __restrict__ rsPacked,   // (64,64) half4 in d_ws, tri'd
    const float* __restrict__ tabRADec,   // (48,48,3) -> LDS half4
    const float* __restrict__ tabCgDec,   // (96,2)    composed -> LDS
    const float* __restrict__ tabLVR,     // (32,32,1) -> LDS half (tri'd)
    const float* __restrict__ tabLV,      // (32,32,4) -> LDS half4 (tri'd)
    const float* __restrict__ tabNHL,     // (32,32,4) -> LDS half4 (tri'd)
    float* __restrict__ out,
    int n)
{
    // 45056 B total -> 3 blocks/CU (135 KB of 160 KB), 24 waves/CU, VGPR<=84.
    __shared__ H4      sRADec[48 * 48];   // 18432 B
    __shared__ __half2 sCgComp[2048];     //  8192 B composed cgEnc∘cgDec
    __shared__ __half  sLVR[1024];        //  2048 B
    __shared__ H4      sLV[1024];         //  8192 B
    __shared__ H4      sNHL[1024];        //  8192 B

    int tid = threadIdx.x;

    for (int j = tid; j < 48 * 48; j += 512) {
        H4 h;
        h.xy = __floats2half2_rn(tabRADec[j * 3 + 0], tabRADec[j * 3 + 1]);
        h.zw = __floats2half2_rn(tabRADec[j * 3 + 2], 0.0f);
        sRADec[j] = h;
    }
#pragma unroll
    for (int k = 0; k < 4; ++k) {
        int j = tid + k * 512;
        // compose: cg = tri(cgEnc[j]); cgCoefs = lerp(cgDec, clamp01(cg)*95)
        float cg = tri_(tabCgEnc[j]);
        float u = clamp01(cg) * 95.0f;
        float u0f = floorf(u);
        float fu = u - u0f;
        int u0 = (int)u0f;
        int u1 = min(u0 + 1, 95);
        float2 a = ((const float2*)tabCgDec)[u0];
        float2 b = ((const float2*)tabCgDec)[u1];
        sCgComp[j] = __floats2half2_rn(a.x * (1.0f - fu) + b.x * fu,
                                       a.y * (1.0f - fu) + b.y * fu);
    }
#pragma unroll
    for (int k = 0; k < 2; ++k) {
        int j = tid + k * 512;
        sLVR[j] = __float2half(tri_(tabLVR[j]));
        float4 v = ((const float4*)tabLV)[j];
        H4 h; h.xy = __floats2half2_rn(tri_(v.x), tri_(v.y));
              h.zw = __floats2half2_rn(tri_(v.z), tri_(v.w));
        sLV[j] = h;
        float4 w = ((const float4*)tabNHL)[j];
        H4 h2; h2.xy = __floats2half2_rn(tri_(w.x), tri_(w.y));
               h2.zw = __floats2half2_rn(tri_(w.z), tri_(w.w));
        sNHL[j] = h2;
    }
    __syncthreads();

    int P = (n + 1) >> 1;        // total pairs
    int H = (P + 1) >> 1;        // far-pair split
    int t = blockIdx.x * 512 + tid;
    if (t >= H) return;
    int p1 = t;
    int p2 = t + H;

    bool full1 = (2 * p1 + 1) < n;
    bool full2 = (p2 < P) && ((2 * p2 + 1) < n);

    if (full1 && full2) {
        // ---- hoist: rN/aT for both pairs, then ALL 4 RAEnc gathers ----
        float4 rN1 = nt_load4(roughNoh + 4 * p1);
        float4 aT1 = nt_load4(anisoToh + 4 * p1);
        float4 rN2 = nt_load4(roughNoh + 4 * p2);
        float4 aT2 = nt_load4(anisoToh + 4 * p2);

        float2 raT0 = gatherRA(tabRAEnc, rN1.x, aT1.x);
        float2 raT1 = gatherRA(tabRAEnc, rN1.z, aT1.z);
        float2 raT2 = gatherRA(tabRAEnc, rN2.x, aT2.x);
        float2 raT3 = gatherRA(tabRAEnc, rN2.z, aT2.z);

        // remaining streams, both pairs (all full-line coalesced)
        float4 nLV1 = nt_load4(nDotLV   + 4 * p1);
        float4 mL1  = nt_load4(metalLoh + 4 * p1);
        float4 sC1  = nt_load4(subCg    + 4 * p1);
        float4 sp1  = nt_load4(spst     + 4 * p1);
        float4 sh1  = nt_load4(shst     + 4 * p1);
        float4 lC1  = nt_load4(lumCs    + 4 * p1);
        float4 nLV2 = nt_load4(nDotLV   + 4 * p2);
        float4 mL2  = nt_load4(metalLoh + 4 * p2);
        float4 sC2  = nt_load4(subCg    + 4 * p2);
        float4 sp2  = nt_load4(spst     + 4 * p2);
        float4 sh2  = nt_load4(shst     + 4 * p2);
        float4 lC2  = nt_load4(lumCs    + 4 * p2);

        float2 r0 = shadeB<USE_WS>(rN1.x, rN1.y, aT1.y, nLV1.x, nLV1.y,
                                   mL1.x, mL1.y, sC1.x, sC1.y, sp1.x, sp1.y,
                                   sh1.x, sh1.y, lC1.x, lC1.y, raT0,
                                   tabRSEnc, rsPacked,
                                   sRADec, sCgComp, sLVR, sLV, sNHL);
        float2 r1 = shadeB<USE_WS>(rN1.z, rN1.w, aT1.w, nLV1.z, nLV1.w,
                                   mL1.z, mL1.w, sC1.z, sC1.w, sp1.z, sp1.w,
                                   sh1.z, sh1.w, lC1.z, lC1.w, raT1,
                                   tabRSEnc, rsPacked,
                                   sRADec, sCgComp, sLVR, sLV, sNHL);
        nt_store4(out + 4 * p1, make_float4(r0.x, r0.y, r1.x, r1.y));

        float2 r2 = shadeB<USE_WS>(rN2.x, rN2.y, aT2.y, nLV2.x, nLV2.y,
                                   mL2.x, mL2.y, sC2.x, sC2.y, sp2.x, sp2.y,
                                   sh2.x, sh2.y, lC2.x, lC2.y, raT2,
                                   tabRSEnc, rsPacked,
                                   sRADec, sCgComp, sLVR, sLV, sNHL);
        float2 r3 = shadeB<USE_WS>(rN2.z, rN2.w, aT2.w, nLV2.z, nLV2.w,
                                   mL2.z, mL2.w, sC2.z, sC2.w, sp2.z, sp2.w,
                                   sh2.z, sh2.w, lC2.z, lC2.w, raT3,
                                   tabRSEnc, rsPacked,
                                   sRADec, sCgComp, sLVR, sLV, sNHL);
        nt_store4(out + 4 * p2, make_float4(r2.x, r2.y, r3.x, r3.y));
    } else {
        // ---- rare tail: per-element scalar path ----
        int es[4] = { 2 * p1, 2 * p1 + 1,
                      (p2 < P) ? 2 * p2 : n, (p2 < P) ? 2 * p2 + 1 : n };
#pragma unroll
        for (int k = 0; k < 4; ++k) {
            int e = es[k];
            if (e >= n) continue;
            float2 rN  = ((const float2*)roughNoh)[e];
            float2 aT  = ((const float2*)anisoToh)[e];
            float2 nLV = ((const float2*)nDotLV)[e];
            float2 mL  = ((const float2*)metalLoh)[e];
            float2 sC  = ((const float2*)subCg)[e];
            float2 sp  = ((const float2*)spst)[e];
            float2 sh  = ((const float2*)shst)[e];
            float2 lC  = ((const float2*)lumCs)[e];
            float2 raT = gatherRA(tabRAEnc, rN.x, aT.x);
            float2 r = shadeB<USE_WS>(rN.x, rN.y, aT.y, nLV.x, nLV.y,
                                      mL.x, mL.y, sC.x, sC.y, sp.x, sp.y,
                                      sh.x, sh.y, lC.x, lC.y, raT,
                                      tabRSEnc, rsPacked,
                                      sRADec, sCgComp, sLVR, sLV, sNHL);
            ((float2*)out)[e] = r;
        }
    }
}

extern "C" void kernel_launch(void* const* d_in, const int* in_sizes, int n_in,
                              void* d_out, int out_size, void* d_ws, size_t ws_size,
                              hipStream_t stream) {
    // 0 roughNoh, 1 anisoToh, 2 nDotLV, 3 tDotLV (UNUSED), 4 metalLoh,
    // 5 subCg, 6 spst, 7 shst, 8 lumCs, 9 tabRAEnc, 10 tabCgEnc, 11 tabRSEnc,
    // 12 tabRADec, 13 tabCgDec, 14 tabLVR, 15 tabLV, 16 tabNHL
    const float* roughNoh = (const float*)d_in[0];
    const float* anisoToh = (const float*)d_in[1];
    const float* nDotLV   = (const float*)d_in[2];
    const float* metalLoh = (const float*)d_in[4];
    const float* subCg    = (const float*)d_in[5];
    const float* spst     = (const float*)d_in[6];
    const float* shst     = (const float*)d_in[7];
    const float* lumCs    = (const float*)d_in[8];
    const float* tabRAEnc = (const float*)d_in[9];
    const float* tabCgEnc = (const float*)d_in[10];
    const float* tabRSEnc = (const float*)d_in[11];
    const float* tabRADec = (const float*)d_in[12];
    const float* tabCgDec = (const float*)d_in[13];
    const float* tabLVR   = (const float*)d_in[14];
    const float* tabLV    = (const float*)d_in[15];
    const float* tabNHL   = (const float*)d_in[16];

    int n = in_sizes[0] / 2;   // (N,2)
    float* out = (float*)d_out;

    const int block = 512;
    int P = (n + 1) / 2;       // pairs
    int H = (P + 1) / 2;       // threads needed (far-pair split)
    int grid = (H + block - 1) / block;

    bool use_ws = ws_size >= (size_t)(64 * 64 * sizeof(H4));
    if (use_ws) {
        prep_rs_kernel<<<(64 * 64 + 255) / 256, 256, 0, stream>>>(tabRSEnc, (H4*)d_ws);
        disney_main<true><<<grid, block, 0, stream>>>(
            roughNoh, anisoToh, nDotLV, metalLoh, subCg, spst, shst, lumCs,
            tabRAEnc, tabCgEnc, tabRSEnc, (const H4*)d_ws,
            tabRADec, tabCgDec, tabLVR, tabLV, tabNHL, out, n);
    } else {
        disney_main<false><<<grid, block, 0, stream>>>(
            roughNoh, anisoToh, nDotLV, metalLoh, subCg, spst, shst, lumCs,
            tabRAEnc, tabCgEnc, tabRSEnc, (const H4*)d_ws,
            tabRADec, tabCgDec, tabLVR, tabLV, tabNHL, out, n);
    }
}